// Round 3
// baseline (3814.229 us; speedup 1.0000x reference)
//
#include <hip/hip_runtime.h>
#include <hip/hip_bf16.h>

using bf16 = __hip_bfloat16;
typedef __attribute__((ext_vector_type(8))) short bf16x8;    // 8 bf16 (4 VGPRs)
typedef __attribute__((ext_vector_type(16))) float f32x16;

#define T_DIM 8192
#define DM    4096
#define DFF   14336

#define MFMA32(va, vb, vc) __builtin_amdgcn_mfma_f32_32x32x16_bf16(va, vb, vc, 0, 0, 0)

// ---------------------------------------------------------------- helpers
__device__ __forceinline__ void gld_lds16(const bf16* gsrc, bf16* ldst) {
  auto* g = (const __attribute__((address_space(1))) unsigned int*)gsrc;
  auto* l = (__attribute__((address_space(3))) unsigned int*)ldst;
  __builtin_amdgcn_global_load_lds(g, l, 16, 0, 0);
}

// Stage one 8KB chunk (512 granules of 16B = 64 rows) of a [rows][64] bf16 tile.
// LDS dest linear (gld_lds requirement); GLOBAL source inverse-swizzled so
// reads apply  byte ^= ((row&7)<<4)  (T2, rule 21).
__device__ __forceinline__ void stage8k(const bf16* __restrict__ gbase, long lda,
                                        long grow0, long k0, bf16* lds_tile,
                                        int gran0, int tid) {
  const int g = gran0 + tid;            // granule index within tile
  const int row = g >> 3, c16 = g & 7;  // 8 granules (128B) per row
  const bf16* src = gbase + (grow0 + row) * lda + k0 + ((long)(c16 ^ (row & 7)) << 3);
  bf16* dst = lds_tile + ((size_t)(gran0 + (tid & ~63)) << 3);  // wave-uniform base
  gld_lds16(src, dst);
}

// Swizzled fragment read for 32x32x16: row 0..255, kk 0..3, hi = lane>>5.
__device__ __forceinline__ bf16x8 ldsfrag32(const bf16* tile, int row, int kk, int hi) {
  int addr = (row << 7) + (kk << 5) + (hi << 4);  // bytes; 128B per row
  addr ^= (row & 7) << 4;                          // T2 XOR swizzle
  return *reinterpret_cast<const bf16x8*>(reinterpret_cast<const char*>(tile) + addr);
}

#define PHASE_MFMA_BEGIN()                            \
  __builtin_amdgcn_s_barrier();                       \
  asm volatile("s_waitcnt lgkmcnt(0)" ::: "memory");  \
  __builtin_amdgcn_sched_barrier(0);                  \
  __builtin_amdgcn_s_setprio(1)

#define PHASE_MFMA_END()                              \
  __builtin_amdgcn_s_setprio(0);                      \
  __builtin_amdgcn_sched_barrier(0);                  \
  __builtin_amdgcn_s_barrier()

// ---------------------------------------------------------------- fp32 -> bf16 cast
__global__ void cast_bf16_kernel(const float* __restrict__ in,
                                 bf16* __restrict__ out, int n4) {
  int idx = blockIdx.x * blockDim.x + threadIdx.x;
  int stride = gridDim.x * blockDim.x;
  for (int i = idx; i < n4; i += stride) {
    const float4 v = reinterpret_cast<const float4*>(in)[i];
    bf16 t[4] = {__float2bfloat16(v.x), __float2bfloat16(v.y),
                 __float2bfloat16(v.z), __float2bfloat16(v.w)};
    reinterpret_cast<ushort4*>(out)[i] = *reinterpret_cast<ushort4*>(t);
  }
}

// ---------------------------------------------------------------- fp32 [R][C] -> bf16 [C][R]
__global__ void transpose_cast_kernel(const float* __restrict__ in,
                                      bf16* __restrict__ out, int R, int C) {
  __shared__ float tile[32][33];
  const int c0 = blockIdx.x * 32, r0 = blockIdx.y * 32;
  const int tx = threadIdx.x, ty = threadIdx.y;  // block (32,8)
#pragma unroll
  for (int j = 0; j < 4; ++j)
    tile[ty + j * 8][tx] = in[(long)(r0 + ty + j * 8) * C + (c0 + tx)];
  __syncthreads();
#pragma unroll
  for (int j = 0; j < 4; ++j)
    out[(long)(c0 + ty + j * 8) * R + (r0 + tx)] =
        __float2bfloat16(tile[tx][ty + j * 8]);
}

// ---------------------------------------------------------------- GEMM1: gate+up fused (8-phase, 32x32x16)
// X:[T][DM], Gt/Ut:[DFF][DM] (W^T row-major). Tile 256x128, BK=64, 8 waves (2x4).
// Per wave: rows wm*128 + mt*32 (mt=0..3), cols wn*32, for BOTH G and U.
// Chunk release: A{0,2} after p1, A{1,3} after p3, G after p1, U after p2.
// All staging targets tile t+2 (current buffer); vmcnt(8) at p4 drains tile t+1.
__global__ __launch_bounds__(512, 2) void gemm_gateup_kernel(
    const bf16* __restrict__ X, const bf16* __restrict__ Gt,
    const bf16* __restrict__ Ut, bf16* __restrict__ H) {
  __shared__ __align__(16) bf16 sA[2][256 * 64];   // 64 KiB
  __shared__ __align__(16) bf16 sG[2][128 * 64];   // 32 KiB
  __shared__ __align__(16) bf16 sU[2][128 * 64];   // 32 KiB

  const int tid = threadIdx.x;
  const int lane = tid & 63, wid = tid >> 6;
  const int wm = wid >> 2, wn = wid & 3;
  const int l31 = lane & 31, hi = lane >> 5;

  const int nwg = gridDim.x, id = blockIdx.x;
  const int swz = (id & 7) * (nwg >> 3) + (id >> 3);
  const int NBN = DFF / 128;  // 112
  const int bm = swz / NBN, bn = swz % NBN;
  const long row0 = (long)bm * 256, col0 = (long)bn * 128;
  const int NK = DM / 64;  // 64

  f32x16 accg[4], accu[4];
#pragma unroll
  for (int mt = 0; mt < 4; ++mt)
#pragma unroll
    for (int r = 0; r < 16; ++r) { accg[mt][r] = 0.f; accu[mt][r] = 0.f; }

  // prologue: tile0 (8 chunks) + tile1 (8 chunks); drain tile0.
  stage8k(X, DM, row0, 0, (bf16*)sA[0], 0, tid);
  stage8k(X, DM, row0, 0, (bf16*)sA[0], 512, tid);
  stage8k(X, DM, row0, 0, (bf16*)sA[0], 1024, tid);
  stage8k(X, DM, row0, 0, (bf16*)sA[0], 1536, tid);
  stage8k(Gt, DM, col0, 0, (bf16*)sG[0], 0, tid);
  stage8k(Gt, DM, col0, 0, (bf16*)sG[0], 512, tid);
  stage8k(Ut, DM, col0, 0, (bf16*)sU[0], 0, tid);
  stage8k(Ut, DM, col0, 0, (bf16*)sU[0], 512, tid);
  stage8k(X, DM, row0, 64, (bf16*)sA[1], 0, tid);
  stage8k(X, DM, row0, 64, (bf16*)sA[1], 512, tid);
  stage8k(X, DM, row0, 64, (bf16*)sA[1], 1024, tid);
  stage8k(X, DM, row0, 64, (bf16*)sA[1], 1536, tid);
  stage8k(Gt, DM, col0, 64, (bf16*)sG[1], 0, tid);
  stage8k(Gt, DM, col0, 64, (bf16*)sG[1], 512, tid);
  stage8k(Ut, DM, col0, 64, (bf16*)sU[1], 0, tid);
  stage8k(Ut, DM, col0, 64, (bf16*)sU[1], 512, tid);
  asm volatile("s_waitcnt vmcnt(8)" ::: "memory");
  __builtin_amdgcn_s_barrier();

  bf16x8 a[2][4], g[4], u[4];

  for (int t = 0; t < NK; ++t) {
    bf16* aCur = (bf16*)sA[t & 1];
    bf16* gCur = (bf16*)sG[t & 1];
    bf16* uCur = (bf16*)sU[t & 1];
    const long k2 = (long)((t + 2) % NK) * 64;

    // ---- phase 1: read A mt0,1 (8) + G (4); MFMA accg[0,1]
#pragma unroll
    for (int mt = 0; mt < 2; ++mt)
#pragma unroll
      for (int kk = 0; kk < 4; ++kk)
        a[mt][kk] = ldsfrag32(aCur, wm * 128 + mt * 32 + l31, kk, hi);
#pragma unroll
    for (int kk = 0; kk < 4; ++kk)
      g[kk] = ldsfrag32(gCur, wn * 32 + l31, kk, hi);
    PHASE_MFMA_BEGIN();
#pragma unroll
    for (int mt = 0; mt < 2; ++mt)
#pragma unroll
      for (int kk = 0; kk < 4; ++kk)
        accg[mt] = MFMA32(a[mt][kk], g[kk], accg[mt]);
    PHASE_MFMA_END();

    // ---- phase 2: read U (4); stage (t+2) A chunks {0,2}; MFMA accu[0,1]
#pragma unroll
    for (int kk = 0; kk < 4; ++kk)
      u[kk] = ldsfrag32(uCur, wn * 32 + l31, kk, hi);
    stage8k(X, DM, row0, k2, aCur, 0, tid);
    stage8k(X, DM, row0, k2, aCur, 1024, tid);
    PHASE_MFMA_BEGIN();
#pragma unroll
    for (int mt = 0; mt < 2; ++mt)
#pragma unroll
      for (int kk = 0; kk < 4; ++kk)
        accu[mt] = MFMA32(a[mt][kk], u[kk], accu[mt]);
    PHASE_MFMA_END();

    // ---- phase 3: read A mt2,3 (8); stage (t+2) G; MFMA accu[2,3]
#pragma unroll
    for (int mt = 0; mt < 2; ++mt)
#pragma unroll
      for (int kk = 0; kk < 4; ++kk)
        a[mt][kk] = ldsfrag32(aCur, wm * 128 + 64 + mt * 32 + l31, kk, hi);
    stage8k(Gt, DM, col0, k2, gCur, 0, tid);
    stage8k(Gt, DM, col0, k2, gCur, 512, tid);
    PHASE_MFMA_BEGIN();
#pragma unroll
    for (int mt = 0; mt < 2; ++mt)
#pragma unroll
      for (int kk = 0; kk < 4; ++kk)
        accu[2 + mt] = MFMA32(a[mt][kk], u[kk], accu[2 + mt]);
    PHASE_MFMA_END();

    // ---- phase 4: stage (t+2) U + A chunks {1,3}; vmcnt(8) drains t+1; MFMA accg[2,3]
    stage8k(Ut, DM, col0, k2, uCur, 0, tid);
    stage8k(Ut, DM, col0, k2, uCur, 512, tid);
    stage8k(X, DM, row0, k2, aCur, 512, tid);
    stage8k(X, DM, row0, k2, aCur, 1536, tid);
    asm volatile("s_waitcnt vmcnt(8)" ::: "memory");
    PHASE_MFMA_BEGIN();
#pragma unroll
    for (int mt = 0; mt < 2; ++mt)
#pragma unroll
      for (int kk = 0; kk < 4; ++kk)
        accg[2 + mt] = MFMA32(a[mt][kk], g[kk], accg[2 + mt]);
    PHASE_MFMA_END();
  }

  // epilogue: H = bf16(silu(gate) * up); C/D: col=lane&31, row=(r&3)+8*(r>>2)+4*hi
  const long col = col0 + wn * 32 + l31;
#pragma unroll
  for (int mt = 0; mt < 4; ++mt) {
    const long rbase = row0 + wm * 128 + mt * 32 + 4 * hi;
#pragma unroll
    for (int r = 0; r < 16; ++r) {
      const long grow = rbase + (r & 3) + 8 * (r >> 2);
      float gv = accg[mt][r];
      float uv = accu[mt][r];
      float hv = (gv / (1.0f + __expf(-gv))) * uv;
      H[grow * DFF + col] = __float2bfloat16(hv);
    }
  }
}

// ---------------------------------------------------------------- GEMM2: out = routing*(H @ Wd)  (8-phase, 32x32x16)
// A:[T][DFF], Bt:[DM][DFF]. Tile 256x256, BK=64, per-wave 128x64 (mt0..3 x n0..1).
// Chunk release: A{0,2} after p1, A{1,3} after p3, B{all} after p2.
__global__ __launch_bounds__(512, 2) void gemm_down_kernel(
    const bf16* __restrict__ A, const bf16* __restrict__ Bt,
    const float* __restrict__ routing, float* __restrict__ out) {
  __shared__ __align__(16) bf16 sA[2][256 * 64];   // 64 KiB
  __shared__ __align__(16) bf16 sB[2][256 * 64];   // 64 KiB

  const int tid = threadIdx.x;
  const int lane = tid & 63, wid = tid >> 6;
  const int wm = wid >> 2, wn = wid & 3;
  const int l31 = lane & 31, hi = lane >> 5;

  const int nwg = gridDim.x, id = blockIdx.x;
  const int swz = (id & 7) * (nwg >> 3) + (id >> 3);
  const int NBN = DM / 256;  // 16
  const int bm = swz / NBN, bn = swz % NBN;
  const long row0 = (long)bm * 256, col0 = (long)bn * 256;
  const int NK = DFF / 64;  // 224

  f32x16 acc[4][2];
#pragma unroll
  for (int mt = 0; mt < 4; ++mt)
#pragma unroll
    for (int n = 0; n < 2; ++n)
#pragma unroll
      for (int r = 0; r < 16; ++r) acc[mt][n][r] = 0.f;

  // prologue
  stage8k(A, DFF, row0, 0, (bf16*)sA[0], 0, tid);
  stage8k(A, DFF, row0, 0, (bf16*)sA[0], 512, tid);
  stage8k(A, DFF, row0, 0, (bf16*)sA[0], 1024, tid);
  stage8k(A, DFF, row0, 0, (bf16*)sA[0], 1536, tid);
  stage8k(Bt, DFF, col0, 0, (bf16*)sB[0], 0, tid);
  stage8k(Bt, DFF, col0, 0, (bf16*)sB[0], 512, tid);
  stage8k(Bt, DFF, col0, 0, (bf16*)sB[0], 1024, tid);
  stage8k(Bt, DFF, col0, 0, (bf16*)sB[0], 1536, tid);
  stage8k(A, DFF, row0, 64, (bf16*)sA[1], 0, tid);
  stage8k(A, DFF, row0, 64, (bf16*)sA[1], 512, tid);
  stage8k(A, DFF, row0, 64, (bf16*)sA[1], 1024, tid);
  stage8k(A, DFF, row0, 64, (bf16*)sA[1], 1536, tid);
  stage8k(Bt, DFF, col0, 64, (bf16*)sB[1], 0, tid);
  stage8k(Bt, DFF, col0, 64, (bf16*)sB[1], 512, tid);
  stage8k(Bt, DFF, col0, 64, (bf16*)sB[1], 1024, tid);
  stage8k(Bt, DFF, col0, 64, (bf16*)sB[1], 1536, tid);
  asm volatile("s_waitcnt vmcnt(8)" ::: "memory");
  __builtin_amdgcn_s_barrier();

  bf16x8 a[2][4], b[2][4];

  for (int t = 0; t < NK; ++t) {
    bf16* aCur = (bf16*)sA[t & 1];
    bf16* bCur = (bf16*)sB[t & 1];
    const long k2 = (long)((t + 2) % NK) * 64;

    // ---- phase 1: read A mt0,1 (8) + B n0 (4); MFMA acc[0..1][0]
#pragma unroll
    for (int mt = 0; mt < 2; ++mt)
#pragma unroll
      for (int kk = 0; kk < 4; ++kk)
        a[mt][kk] = ldsfrag32(aCur, wm * 128 + mt * 32 + l31, kk, hi);
#pragma unroll
    for (int kk = 0; kk < 4; ++kk)
      b[0][kk] = ldsfrag32(bCur, wn * 64 + l31, kk, hi);
    PHASE_MFMA_BEGIN();
#pragma unroll
    for (int mt = 0; mt < 2; ++mt)
#pragma unroll
      for (int kk = 0; kk < 4; ++kk)
        acc[mt][0] = MFMA32(a[mt][kk], b[0][kk], acc[mt][0]);
    PHASE_MFMA_END();

    // ---- phase 2: read B n1 (4); stage (t+2) A{0,2}; MFMA acc[0..1][1]
#pragma unroll
    for (int kk = 0; kk < 4; ++kk)
      b[1][kk] = ldsfrag32(bCur, wn * 64 + 32 + l31, kk, hi);
    stage8k(A, DFF, row0, k2, aCur, 0, tid);
    stage8k(A, DFF, row0, k2, aCur, 1024, tid);
    PHASE_MFMA_BEGIN();
#pragma unroll
    for (int mt = 0; mt < 2; ++mt)
#pragma unroll
      for (int kk = 0; kk < 4; ++kk)
        acc[mt][1] = MFMA32(a[mt][kk], b[1][kk], acc[mt][1]);
    PHASE_MFMA_END();

    // ---- phase 3: read A mt2,3 (8); stage (t+2) B{0,1}; MFMA acc[2..3][1]
#pragma unroll
    for (int mt = 0; mt < 2; ++mt)
#pragma unroll
      for (int kk = 0; kk < 4; ++kk)
        a[mt][kk] = ldsfrag32(aCur, wm * 128 + 64 + mt * 32 + l31, kk, hi);
    stage8k(Bt, DFF, col0, k2, bCur, 0, tid);
    stage8k(Bt, DFF, col0, k2, bCur, 512, tid);
    PHASE_MFMA_BEGIN();
#pragma unroll
    for (int mt = 0; mt < 2; ++mt)
#pragma unroll
      for (int kk = 0; kk < 4; ++kk)
        acc[2 + mt][1] = MFMA32(a[mt][kk], b[1][kk], acc[2 + mt][1]);
    PHASE_MFMA_END();

    // ---- phase 4: stage (t+2) B{2,3} + A{1,3}; vmcnt(8); MFMA acc[2..3][0]
    stage8k(Bt, DFF, col0, k2, bCur, 1024, tid);
    stage8k(Bt, DFF, col0, k2, bCur, 1536, tid);
    stage8k(A, DFF, row0, k2, aCur, 512, tid);
    stage8k(A, DFF, row0, k2, aCur, 1536, tid);
    asm volatile("s_waitcnt vmcnt(8)" ::: "memory");
    PHASE_MFMA_BEGIN();
#pragma unroll
    for (int mt = 0; mt < 2; ++mt)
#pragma unroll
      for (int kk = 0; kk < 4; ++kk)
        acc[2 + mt][0] = MFMA32(a[mt][kk], b[0][kk], acc[2 + mt][0]);
    PHASE_MFMA_END();
  }

  // epilogue: out = routing[r] * acc
#pragma unroll
  for (int mt = 0; mt < 4; ++mt) {
    const long rbase = row0 + wm * 128 + mt * 32 + 4 * hi;
#pragma unroll
    for (int r = 0; r < 16; ++r) {
      const long grow = rbase + (r & 3) + 8 * (r >> 2);
      const float rv = routing[grow];
#pragma unroll
      for (int n = 0; n < 2; ++n)
        out[grow * DM + (col0 + wn * 64 + n * 32 + l31)] = rv * acc[mt][n][r];
    }
  }
}

// ---------------------------------------------------------------- launch
extern "C" void kernel_launch(void* const* d_in, const int* in_sizes, int n_in,
                              void* d_out, int out_size, void* d_ws, size_t ws_size,
                              hipStream_t stream) {
  const float* X  = (const float*)d_in[0];
  const float* rw = (const float*)d_in[1];
  const float* Wg = (const float*)d_in[2];
  const float* Wu = (const float*)d_in[3];
  const float* Wd = (const float*)d_in[4];
  float* out = (float*)d_out;

  char* ws = (char*)d_ws;
  size_t off = 0;
  bf16* Xb = (bf16*)(ws + off); off += (size_t)T_DIM * DM * 2;   // 64 MiB
  bf16* GT = (bf16*)(ws + off); off += (size_t)DM * DFF * 2;     // 112 MiB
  bf16* UT = (bf16*)(ws + off); off += (size_t)DM * DFF * 2;     // 112 MiB
  bf16* DT = (bf16*)(ws + off); off += (size_t)DM * DFF * 2;     // 112 MiB
  bf16* Hb = (bf16*)(ws + off); off += (size_t)T_DIM * DFF * 2;  // 224 MiB

  cast_bf16_kernel<<<2048, 256, 0, stream>>>(X, Xb, T_DIM * DM / 4);
  dim3 tpb(32, 8);
  transpose_cast_kernel<<<dim3(DFF / 32, DM / 32), tpb, 0, stream>>>(Wg, GT, DM, DFF);
  transpose_cast_kernel<<<dim3(DFF / 32, DM / 32), tpb, 0, stream>>>(Wu, UT, DM, DFF);
  transpose_cast_kernel<<<dim3(DM / 32, DFF / 32), tpb, 0, stream>>>(Wd, DT, DFF, DM);

  gemm_gateup_kernel<<<(T_DIM / 256) * (DFF / 128), 512, 0, stream>>>(Xb, GT, UT, Hb);
  gemm_down_kernel<<<(T_DIM / 256) * (DM / 256), 512, 0, stream>>>(Hb, DT, rw, out);
}

// Round 4
// 3413.565 us; speedup vs baseline: 1.1174x; 1.1174x over previous
//
#include <hip/hip_runtime.h>
#include <hip/hip_bf16.h>

using bf16 = __hip_bfloat16;
typedef __attribute__((ext_vector_type(8))) short bf16x8;   // 8 bf16 (4 VGPRs)
typedef __attribute__((ext_vector_type(4))) float f32x4;

#define T_DIM 8192
#define DM    4096
#define DFF   14336

#define MFMA(va, vb, vc) __builtin_amdgcn_mfma_f32_16x16x32_bf16(va, vb, vc, 0, 0, 0)

// ---------------------------------------------------------------- helpers
__device__ __forceinline__ void gld_lds16(const bf16* gsrc, bf16* ldst) {
  auto* g = (const __attribute__((address_space(1))) unsigned int*)gsrc;
  auto* l = (__attribute__((address_space(3))) unsigned int*)ldst;
  __builtin_amdgcn_global_load_lds(g, l, 16, 0, 0);
}

// Stage one 8KB chunk (512 granules of 16B = 64 rows) of a [rows][64] bf16 tile.
// LDS dest linear (gld_lds requirement); GLOBAL source inverse-swizzled so
// reads apply  byte ^= ((row&7)<<4)  (T2, rule 21).
__device__ __forceinline__ void stage8k(const bf16* __restrict__ gbase, long lda,
                                        long grow0, long k0, bf16* lds_tile,
                                        int gran0, int tid) {
  const int g = gran0 + tid;            // granule index within tile
  const int row = g >> 3, c16 = g & 7;  // 8 granules (128B) per row
  const bf16* src = gbase + (grow0 + row) * lda + k0 + ((long)(c16 ^ (row & 7)) << 3);
  bf16* dst = lds_tile + ((size_t)(gran0 + (tid & ~63)) << 3);  // wave-uniform base
  gld_lds16(src, dst);
}

// Swizzled fragment read: 8 contiguous k (bf16) for MFMA A/B operand (16x16x32).
__device__ __forceinline__ bf16x8 ldsfrag(const bf16* tile, int row, int kk, int fg) {
  int addr = (row << 7) + (kk << 6) + (fg << 4);  // bytes; 128B per row
  addr ^= (row & 7) << 4;                          // T2 XOR swizzle
  return *reinterpret_cast<const bf16x8*>(reinterpret_cast<const char*>(tile) + addr);
}

#define PHASE_MFMA_BEGIN()                            \
  __builtin_amdgcn_s_barrier();                       \
  asm volatile("s_waitcnt lgkmcnt(0)" ::: "memory");  \
  __builtin_amdgcn_sched_barrier(0);                  \
  __builtin_amdgcn_s_setprio(1)

#define PHASE_MFMA_END()                              \
  __builtin_amdgcn_s_setprio(0);                      \
  __builtin_amdgcn_sched_barrier(0);                  \
  __builtin_amdgcn_s_barrier()

// ---------------------------------------------------------------- fp32 -> bf16 cast
__global__ void cast_bf16_kernel(const float* __restrict__ in,
                                 bf16* __restrict__ out, int n4) {
  int idx = blockIdx.x * blockDim.x + threadIdx.x;
  int stride = gridDim.x * blockDim.x;
  for (int i = idx; i < n4; i += stride) {
    const float4 v = reinterpret_cast<const float4*>(in)[i];
    bf16 t[4] = {__float2bfloat16(v.x), __float2bfloat16(v.y),
                 __float2bfloat16(v.z), __float2bfloat16(v.w)};
    reinterpret_cast<ushort4*>(out)[i] = *reinterpret_cast<ushort4*>(t);
  }
}

// ---------------------------------------------------------------- fp32 [R][C] -> bf16 [C][R]
__global__ void transpose_cast_kernel(const float* __restrict__ in,
                                      bf16* __restrict__ out, int R, int C) {
  __shared__ float tile[32][33];
  const int c0 = blockIdx.x * 32, r0 = blockIdx.y * 32;
  const int tx = threadIdx.x, ty = threadIdx.y;  // block (32,8)
#pragma unroll
  for (int j = 0; j < 4; ++j)
    tile[ty + j * 8][tx] = in[(long)(r0 + ty + j * 8) * C + (c0 + tx)];
  __syncthreads();
#pragma unroll
  for (int j = 0; j < 4; ++j)
    out[(long)(c0 + ty + j * 8) * R + (r0 + tx)] =
        __float2bfloat16(tile[tx][ty + j * 8]);
}

// ---------------------------------------------------------------- GEMM1: gate+up fused (8-phase, m201 geometry)
// X:[T][DM], Gt/Ut:[DFF][DM] (W^T row-major).
// Tile 256(M) x 256(N'), where B rows 0-127 = Gt[fcol0..+128), rows 128-255 =
// Ut[fcol0..+128). BK=64, 8 waves (2x4), per-wave 128x64, acc[8][4].
// Wave's gate frag acc[m][n] (n=0,1) and up frag acc[m][n+2] hold the SAME
// (row, H-col) in the same lane -> SwiGLU combine is register-only.
__global__ __launch_bounds__(512, 2) void gemm_gateup_kernel(
    const bf16* __restrict__ X, const bf16* __restrict__ Gt,
    const bf16* __restrict__ Ut, bf16* __restrict__ H) {
  __shared__ __align__(16) bf16 sA[2][256 * 64];   // 64 KiB
  __shared__ __align__(16) bf16 sB[2][256 * 64];   // 64 KiB

  const int tid = threadIdx.x;
  const int lane = tid & 63, wid = tid >> 6;
  const int wm = wid >> 2, wn = wid & 3;
  const int fr = lane & 15, fg = lane >> 4;

  const int nwg = gridDim.x, id = blockIdx.x;
  const int swz = (id & 7) * (nwg >> 3) + (id >> 3);
  const int NBN = DFF / 128;  // 112
  const int bm = swz / NBN, bn = swz % NBN;
  const long row0 = (long)bm * 256;
  const long fcol0 = (long)bn * 128;   // H col block == Gt/Ut row block
  const int NK = DM / 64;  // 64

  f32x4 acc[8][4];  // n=0,1: gate; n=2,3: up (same H cols)
  const f32x4 z = {0.f, 0.f, 0.f, 0.f};
#pragma unroll
  for (int m = 0; m < 8; ++m)
#pragma unroll
    for (int n = 0; n < 4; ++n) acc[m][n] = z;

  // prologue: K0 full (A x4, B x4), K1 partial (A0, B x4). K1's A1 at p1 of t=0.
  stage8k(X, DM, row0, 0, (bf16*)sA[0], 0, tid);
  stage8k(X, DM, row0, 0, (bf16*)sA[0], 512, tid);
  stage8k(X, DM, row0, 0, (bf16*)sA[0], 1024, tid);
  stage8k(X, DM, row0, 0, (bf16*)sA[0], 1536, tid);
  stage8k(Gt, DM, fcol0, 0, (bf16*)sB[0], 0, tid);
  stage8k(Gt, DM, fcol0, 0, (bf16*)sB[0], 512, tid);
  stage8k(Ut, DM, fcol0 - 128, 0, (bf16*)sB[0], 1024, tid);
  stage8k(Ut, DM, fcol0 - 128, 0, (bf16*)sB[0], 1536, tid);
  stage8k(X, DM, row0, 64, (bf16*)sA[1], 0, tid);
  stage8k(X, DM, row0, 64, (bf16*)sA[1], 512, tid);
  stage8k(Gt, DM, fcol0, 64, (bf16*)sB[1], 0, tid);
  stage8k(Gt, DM, fcol0, 64, (bf16*)sB[1], 512, tid);
  stage8k(Ut, DM, fcol0 - 128, 64, (bf16*)sB[1], 1024, tid);
  stage8k(Ut, DM, fcol0 - 128, 64, (bf16*)sB[1], 1536, tid);
  asm volatile("s_waitcnt vmcnt(6)" ::: "memory");
  __builtin_amdgcn_s_barrier();

  bf16x8 a[4][2], b[4][2];

  for (int t = 0; t < NK; ++t) {
    bf16* aCur = (bf16*)sA[t & 1];
    bf16* bCur = (bf16*)sB[t & 1];
    bf16* aNxt = (bf16*)sA[(t + 1) & 1];
    const long k1 = (long)((t + 1) % NK) * 64;  // wrap: tail stages land harmlessly
    const long k2 = (long)((t + 2) % NK) * 64;

    // ---- phase 1: read A-mh0 (8) + B-nh0/gate (4); stage (t+1)A1; MFMA Q(mh0, gate)
#pragma unroll
    for (int m = 0; m < 4; ++m)
#pragma unroll
      for (int kk = 0; kk < 2; ++kk)
        a[m][kk] = ldsfrag(aCur, m * 32 + wm * 16 + fr, kk, fg);
#pragma unroll
    for (int n = 0; n < 2; ++n)
#pragma unroll
      for (int kk = 0; kk < 2; ++kk)
        b[n][kk] = ldsfrag(bCur, n * 64 + wn * 16 + fr, kk, fg);
    stage8k(X, DM, row0, k1, aNxt, 1024, tid);
    stage8k(X, DM, row0, k1, aNxt, 1536, tid);
    PHASE_MFMA_BEGIN();
#pragma unroll
    for (int m = 0; m < 4; ++m)
#pragma unroll
      for (int n = 0; n < 2; ++n)
#pragma unroll
        for (int kk = 0; kk < 2; ++kk)
          acc[m][n] = MFMA(a[m][kk], b[n][kk], acc[m][n]);
    PHASE_MFMA_END();

    // ---- phase 2: read B-nh1/up (4); stage (t+2)A0; MFMA Q(mh0, up)
#pragma unroll
    for (int n = 2; n < 4; ++n)
#pragma unroll
      for (int kk = 0; kk < 2; ++kk)
        b[n][kk] = ldsfrag(bCur, n * 64 + wn * 16 + fr, kk, fg);
    stage8k(X, DM, row0, k2, aCur, 0, tid);
    stage8k(X, DM, row0, k2, aCur, 512, tid);
    PHASE_MFMA_BEGIN();
#pragma unroll
    for (int m = 0; m < 4; ++m)
#pragma unroll
      for (int n = 2; n < 4; ++n)
#pragma unroll
        for (int kk = 0; kk < 2; ++kk)
          acc[m][n] = MFMA(a[m][kk], b[n][kk], acc[m][n]);
    PHASE_MFMA_END();

    // ---- phase 3: read A-mh1 (8); stage (t+2)B-gate; MFMA Q(mh1, up)
#pragma unroll
    for (int m = 0; m < 4; ++m)
#pragma unroll
      for (int kk = 0; kk < 2; ++kk)
        a[m][kk] = ldsfrag(aCur, 128 + m * 32 + wm * 16 + fr, kk, fg);
    stage8k(Gt, DM, fcol0, k2, bCur, 0, tid);
    stage8k(Gt, DM, fcol0, k2, bCur, 512, tid);
    PHASE_MFMA_BEGIN();
#pragma unroll
    for (int m = 0; m < 4; ++m)
#pragma unroll
      for (int n = 2; n < 4; ++n)
#pragma unroll
        for (int kk = 0; kk < 2; ++kk)
          acc[4 + m][n] = MFMA(a[m][kk], b[n][kk], acc[4 + m][n]);
    PHASE_MFMA_END();

    // ---- phase 4: stage (t+2)B-up; vmcnt(6); MFMA Q(mh1, gate)
    stage8k(Ut, DM, fcol0 - 128, k2, bCur, 1024, tid);
    stage8k(Ut, DM, fcol0 - 128, k2, bCur, 1536, tid);
    asm volatile("s_waitcnt vmcnt(6)" ::: "memory");
    PHASE_MFMA_BEGIN();
#pragma unroll
    for (int m = 0; m < 4; ++m)
#pragma unroll
      for (int n = 0; n < 2; ++n)
#pragma unroll
        for (int kk = 0; kk < 2; ++kk)
          acc[4 + m][n] = MFMA(a[m][kk], b[n][kk], acc[4 + m][n]);
    PHASE_MFMA_END();
  }

  // epilogue: H = bf16(silu(gate) * up) — register-only pairing
#pragma unroll
  for (int m = 0; m < 8; ++m) {
    const long rbase = row0 + m * 32 + wm * 16 + fg * 4;
#pragma unroll
    for (int n = 0; n < 2; ++n) {
      const long c = fcol0 + n * 64 + wn * 16 + fr;
#pragma unroll
      for (int i = 0; i < 4; ++i) {
        float gv = acc[m][n][i];
        float uv = acc[m][n + 2][i];
        float hv = (gv / (1.0f + __expf(-gv))) * uv;
        H[(rbase + i) * DFF + c] = __float2bfloat16(hv);
      }
    }
  }
}

// ---------------------------------------------------------------- GEMM2: out = routing*(H @ Wd)  (8-phase, m201 geometry)
// A:[T][DFF], Bt:[DM][DFF]. Tile 256x256, BK=64, per-wave 128x64, acc[8][4].
__global__ __launch_bounds__(512, 2) void gemm_down_kernel(
    const bf16* __restrict__ A, const bf16* __restrict__ Bt,
    const float* __restrict__ routing, float* __restrict__ out) {
  __shared__ __align__(16) bf16 sA[2][256 * 64];   // 64 KiB
  __shared__ __align__(16) bf16 sB[2][256 * 64];   // 64 KiB

  const int tid = threadIdx.x;
  const int lane = tid & 63, wid = tid >> 6;
  const int wm = wid >> 2, wn = wid & 3;
  const int fr = lane & 15, fg = lane >> 4;

  const int nwg = gridDim.x, id = blockIdx.x;
  const int swz = (id & 7) * (nwg >> 3) + (id >> 3);
  const int NBN = DM / 256;  // 16
  const int bm = swz / NBN, bn = swz % NBN;
  const long row0 = (long)bm * 256, col0 = (long)bn * 256;
  const int NK = DFF / 64;  // 224

  f32x4 acc[8][4];
  const f32x4 z = {0.f, 0.f, 0.f, 0.f};
#pragma unroll
  for (int m = 0; m < 8; ++m)
#pragma unroll
    for (int n = 0; n < 4; ++n) acc[m][n] = z;

  // prologue: K0 full (A0,A1,B0,B1), K1 partial (A0,B0,B1)
  stage8k(A, DFF, row0, 0, (bf16*)sA[0], 0, tid);
  stage8k(A, DFF, row0, 0, (bf16*)sA[0], 512, tid);
  stage8k(A, DFF, row0, 0, (bf16*)sA[0], 1024, tid);
  stage8k(A, DFF, row0, 0, (bf16*)sA[0], 1536, tid);
  stage8k(Bt, DFF, col0, 0, (bf16*)sB[0], 0, tid);
  stage8k(Bt, DFF, col0, 0, (bf16*)sB[0], 512, tid);
  stage8k(Bt, DFF, col0, 0, (bf16*)sB[0], 1024, tid);
  stage8k(Bt, DFF, col0, 0, (bf16*)sB[0], 1536, tid);
  stage8k(A, DFF, row0, 64, (bf16*)sA[1], 0, tid);
  stage8k(A, DFF, row0, 64, (bf16*)sA[1], 512, tid);
  stage8k(Bt, DFF, col0, 64, (bf16*)sB[1], 0, tid);
  stage8k(Bt, DFF, col0, 64, (bf16*)sB[1], 512, tid);
  stage8k(Bt, DFF, col0, 64, (bf16*)sB[1], 1024, tid);
  stage8k(Bt, DFF, col0, 64, (bf16*)sB[1], 1536, tid);
  asm volatile("s_waitcnt vmcnt(6)" ::: "memory");
  __builtin_amdgcn_s_barrier();

  bf16x8 a[4][2], b[4][2];

  for (int t = 0; t < NK; ++t) {
    bf16* aCur = (bf16*)sA[t & 1];
    bf16* bCur = (bf16*)sB[t & 1];
    bf16* aNxt = (bf16*)sA[(t + 1) & 1];
    const long k1 = (long)((t + 1) % NK) * 64;
    const long k2 = (long)((t + 2) % NK) * 64;

    // ---- phase 1: read A-mh0 (8) + B-nh0 (4); stage (t+1)A1; MFMA Q(mh0,nh0)
#pragma unroll
    for (int m = 0; m < 4; ++m)
#pragma unroll
      for (int kk = 0; kk < 2; ++kk)
        a[m][kk] = ldsfrag(aCur, m * 32 + wm * 16 + fr, kk, fg);
#pragma unroll
    for (int n = 0; n < 2; ++n)
#pragma unroll
      for (int kk = 0; kk < 2; ++kk)
        b[n][kk] = ldsfrag(bCur, n * 64 + wn * 16 + fr, kk, fg);
    stage8k(A, DFF, row0, k1, aNxt, 1024, tid);
    stage8k(A, DFF, row0, k1, aNxt, 1536, tid);
    PHASE_MFMA_BEGIN();
#pragma unroll
    for (int m = 0; m < 4; ++m)
#pragma unroll
      for (int n = 0; n < 2; ++n)
#pragma unroll
        for (int kk = 0; kk < 2; ++kk)
          acc[m][n] = MFMA(a[m][kk], b[n][kk], acc[m][n]);
    PHASE_MFMA_END();

    // ---- phase 2: read B-nh1 (4); stage (t+2)A0; MFMA Q(mh0,nh1)
#pragma unroll
    for (int n = 2; n < 4; ++n)
#pragma unroll
      for (int kk = 0; kk < 2; ++kk)
        b[n][kk] = ldsfrag(bCur, n * 64 + wn * 16 + fr, kk, fg);
    stage8k(A, DFF, row0, k2, aCur, 0, tid);
    stage8k(A, DFF, row0, k2, aCur, 512, tid);
    PHASE_MFMA_BEGIN();
#pragma unroll
    for (int m = 0; m < 4; ++m)
#pragma unroll
      for (int n = 2; n < 4; ++n)
#pragma unroll
        for (int kk = 0; kk < 2; ++kk)
          acc[m][n] = MFMA(a[m][kk], b[n][kk], acc[m][n]);
    PHASE_MFMA_END();

    // ---- phase 3: read A-mh1 (8); stage (t+2)B0; MFMA Q(mh1,nh1)
#pragma unroll
    for (int m = 0; m < 4; ++m)
#pragma unroll
      for (int kk = 0; kk < 2; ++kk)
        a[m][kk] = ldsfrag(aCur, 128 + m * 32 + wm * 16 + fr, kk, fg);
    stage8k(Bt, DFF, col0, k2, bCur, 0, tid);
    stage8k(Bt, DFF, col0, k2, bCur, 512, tid);
    PHASE_MFMA_BEGIN();
#pragma unroll
    for (int m = 0; m < 4; ++m)
#pragma unroll
      for (int n = 2; n < 4; ++n)
#pragma unroll
        for (int kk = 0; kk < 2; ++kk)
          acc[4 + m][n] = MFMA(a[m][kk], b[n][kk], acc[4 + m][n]);
    PHASE_MFMA_END();

    // ---- phase 4: stage (t+2)B1; vmcnt(6); MFMA Q(mh1,nh0)
    stage8k(Bt, DFF, col0, k2, bCur, 1024, tid);
    stage8k(Bt, DFF, col0, k2, bCur, 1536, tid);
    asm volatile("s_waitcnt vmcnt(6)" ::: "memory");
    PHASE_MFMA_BEGIN();
#pragma unroll
    for (int m = 0; m < 4; ++m)
#pragma unroll
      for (int n = 0; n < 2; ++n)
#pragma unroll
        for (int kk = 0; kk < 2; ++kk)
          acc[4 + m][n] = MFMA(a[m][kk], b[n][kk], acc[4 + m][n]);
    PHASE_MFMA_END();
  }

  // epilogue: out = routing[r] * acc
#pragma unroll
  for (int m = 0; m < 8; ++m) {
    const long r0w = row0 + m * 32 + wm * 16 + fg * 4;
#pragma unroll
    for (int i = 0; i < 4; ++i) {
      const long r = r0w + i;
      const float rv = routing[r];
#pragma unroll
      for (int n = 0; n < 4; ++n)
        out[r * DM + (col0 + n * 64 + wn * 16 + fr)] = rv * acc[m][n][i];
    }
  }
}

// ---------------------------------------------------------------- launch
extern "C" void kernel_launch(void* const* d_in, const int* in_sizes, int n_in,
                              void* d_out, int out_size, void* d_ws, size_t ws_size,
                              hipStream_t stream) {
  const float* X  = (const float*)d_in[0];
  const float* rw = (const float*)d_in[1];
  const float* Wg = (const float*)d_in[2];
  const float* Wu = (const float*)d_in[3];
  const float* Wd = (const float*)d_in[4];
  float* out = (float*)d_out;

  char* ws = (char*)d_ws;
  size_t off = 0;
  bf16* Xb = (bf16*)(ws + off); off += (size_t)T_DIM * DM * 2;   // 64 MiB
  bf16* GT = (bf16*)(ws + off); off += (size_t)DM * DFF * 2;     // 112 MiB
  bf16* UT = (bf16*)(ws + off); off += (size_t)DM * DFF * 2;     // 112 MiB
  bf16* DT = (bf16*)(ws + off); off += (size_t)DM * DFF * 2;     // 112 MiB
  bf16* Hb = (bf16*)(ws + off); off += (size_t)T_DIM * DFF * 2;  // 224 MiB

  cast_bf16_kernel<<<2048, 256, 0, stream>>>(X, Xb, T_DIM * DM / 4);
  dim3 tpb(32, 8);
  transpose_cast_kernel<<<dim3(DFF / 32, DM / 32), tpb, 0, stream>>>(Wg, GT, DM, DFF);
  transpose_cast_kernel<<<dim3(DFF / 32, DM / 32), tpb, 0, stream>>>(Wu, UT, DM, DFF);
  transpose_cast_kernel<<<dim3(DM / 32, DFF / 32), tpb, 0, stream>>>(Wd, DT, DFF, DM);

  gemm_gateup_kernel<<<(T_DIM / 256) * (DFF / 128), 512, 0, stream>>>(Xb, GT, UT, Hb);
  gemm_down_kernel<<<(T_DIM / 256) * (DM / 256), 512, 0, stream>>>(Hb, DT, rw, out);
}

// Round 5
// 3202.649 us; speedup vs baseline: 1.1910x; 1.0659x over previous
//
#include <hip/hip_runtime.h>
#include <hip/hip_bf16.h>

using bf16 = __hip_bfloat16;
typedef __attribute__((ext_vector_type(8))) short bf16x8;   // 8 bf16 (4 VGPRs)
typedef __attribute__((ext_vector_type(4))) float f32x4;

#define T_DIM 8192
#define DM    4096
#define DFF   14336

#define MFMA(va, vb, vc) __builtin_amdgcn_mfma_f32_16x16x32_bf16(va, vb, vc, 0, 0, 0)

// ---------------------------------------------------------------- helpers
__device__ __forceinline__ void gld_lds16(const bf16* gsrc, bf16* ldst) {
  auto* g = (const __attribute__((address_space(1))) unsigned int*)gsrc;
  auto* l = (__attribute__((address_space(3))) unsigned int*)ldst;
  __builtin_amdgcn_global_load_lds(g, l, 16, 0, 0);
}

// Stage one 8KB chunk (512 granules of 16B = 64 rows) of a [rows][64] bf16 tile.
// LDS dest linear (gld_lds requirement); GLOBAL source inverse-swizzled so
// reads apply  byte ^= ((row&7)<<4)  (T2, rule 21).
__device__ __forceinline__ void stage8k(const bf16* __restrict__ gbase, long lda,
                                        long grow0, long k0, bf16* lds_tile,
                                        int gran0, int tid) {
  const int g = gran0 + tid;            // granule index within tile
  const int row = g >> 3, c16 = g & 7;  // 8 granules (128B) per row
  const bf16* src = gbase + (grow0 + row) * lda + k0 + ((long)(c16 ^ (row & 7)) << 3);
  bf16* dst = lds_tile + ((size_t)(gran0 + (tid & ~63)) << 3);  // wave-uniform base
  gld_lds16(src, dst);
}

// Swizzled fragment read: 8 contiguous k (bf16) for MFMA A/B operand (16x16x32).
__device__ __forceinline__ bf16x8 ldsfrag(const bf16* tile, int row, int kk, int fg) {
  int addr = (row << 7) + (kk << 6) + (fg << 4);  // bytes; 128B per row
  addr ^= (row & 7) << 4;                          // T2 XOR swizzle
  return *reinterpret_cast<const bf16x8*>(reinterpret_cast<const char*>(tile) + addr);
}

#define PHASE_MFMA_BEGIN()                            \
  __builtin_amdgcn_s_barrier();                       \
  asm volatile("s_waitcnt lgkmcnt(0)" ::: "memory");  \
  __builtin_amdgcn_sched_barrier(0);                  \
  __builtin_amdgcn_s_setprio(1)

#define PHASE_MFMA_END()                              \
  __builtin_amdgcn_s_setprio(0);                      \
  __builtin_amdgcn_sched_barrier(0);                  \
  __builtin_amdgcn_s_barrier()

// ---------------------------------------------------------------- fp32 [T][DM] -> bf16 [T][xlda] (padded rows)
__global__ void cast_pad_kernel(const float* __restrict__ in,
                                bf16* __restrict__ out, long xlda, int n8) {
  int idx = blockIdx.x * blockDim.x + threadIdx.x;
  int stride = gridDim.x * blockDim.x;
  for (int i = idx; i < n8; i += stride) {
    const int row = i >> 9;              // DM/8 = 512 groups per row
    const int c8 = i & 511;
    const float4 v0 = reinterpret_cast<const float4*>(in)[(long)i * 2];
    const float4 v1 = reinterpret_cast<const float4*>(in)[(long)i * 2 + 1];
    bf16 t[8] = {__float2bfloat16(v0.x), __float2bfloat16(v0.y),
                 __float2bfloat16(v0.z), __float2bfloat16(v0.w),
                 __float2bfloat16(v1.x), __float2bfloat16(v1.y),
                 __float2bfloat16(v1.z), __float2bfloat16(v1.w)};
    *reinterpret_cast<bf16x8*>(&out[(long)row * xlda + (long)c8 * 8]) =
        *reinterpret_cast<bf16x8*>(t);
  }
}

// ---------------------------------------------------------------- fp32 [R][C] -> bf16 [C][out_lda] (transposed, padded rows)
__global__ void transpose_cast_kernel(const float* __restrict__ in,
                                      bf16* __restrict__ out, int R, int C,
                                      long out_lda) {
  __shared__ float tile[32][33];
  const int c0 = blockIdx.x * 32, r0 = blockIdx.y * 32;
  const int tx = threadIdx.x, ty = threadIdx.y;  // block (32,8)
#pragma unroll
  for (int j = 0; j < 4; ++j)
    tile[ty + j * 8][tx] = in[(long)(r0 + ty + j * 8) * C + (c0 + tx)];
  __syncthreads();
#pragma unroll
  for (int j = 0; j < 4; ++j)
    out[(long)(c0 + ty + j * 8) * out_lda + (r0 + tx)] =
        __float2bfloat16(tile[tx][ty + j * 8]);
}

// ---------------------------------------------------------------- GEMM1: gate+up fused (8-phase, m201 geometry)
// X:[T][ldx], Gt/Ut:[DFF][ldw] (W^T row-major, padded).
// Tile 256(M) x 256(N'): B rows 0-127 = Gt[fcol0..+128), 128-255 = Ut[fcol0..+128).
// XCD-partitioned: xcd owns 14 consecutive f-blocks; bm advances co-temporally.
__global__ __launch_bounds__(512, 2) void gemm_gateup_kernel(
    const bf16* __restrict__ X, const bf16* __restrict__ Gt,
    const bf16* __restrict__ Ut, bf16* __restrict__ H,
    long ldx, long ldw, long ldh) {
  __shared__ __align__(16) bf16 sA[2][256 * 64];   // 64 KiB
  __shared__ __align__(16) bf16 sB[2][256 * 64];   // 64 KiB

  const int tid = threadIdx.x;
  const int lane = tid & 63, wid = tid >> 6;
  const int wm = wid >> 2, wn = wid & 3;
  const int fr = lane & 15, fg = lane >> 4;

  // XCD ownership: xcd = id&7 owns f-blocks [xcd*14, xcd*14+14); bm = j/14.
  const int id = blockIdx.x;
  const int xcd = id & 7, j = id >> 3;
  const int bm = j / 14, bnl = j % 14;
  const long row0 = (long)bm * 256;
  const long fcol0 = (long)(xcd * 14 + bnl) * 128;  // H col block == Gt/Ut row block
  const int NK = DM / 64;  // 64

  f32x4 acc[8][4];  // n=0,1: gate; n=2,3: up (same H cols)
  const f32x4 z = {0.f, 0.f, 0.f, 0.f};
#pragma unroll
  for (int m = 0; m < 8; ++m)
#pragma unroll
    for (int n = 0; n < 4; ++n) acc[m][n] = z;

  // prologue: K0 full (A x4, B x4), K1 partial (A0, B x4). K1's A1 at p1 of t=0.
  stage8k(X, ldx, row0, 0, (bf16*)sA[0], 0, tid);
  stage8k(X, ldx, row0, 0, (bf16*)sA[0], 512, tid);
  stage8k(X, ldx, row0, 0, (bf16*)sA[0], 1024, tid);
  stage8k(X, ldx, row0, 0, (bf16*)sA[0], 1536, tid);
  stage8k(Gt, ldw, fcol0, 0, (bf16*)sB[0], 0, tid);
  stage8k(Gt, ldw, fcol0, 0, (bf16*)sB[0], 512, tid);
  stage8k(Ut, ldw, fcol0 - 128, 0, (bf16*)sB[0], 1024, tid);
  stage8k(Ut, ldw, fcol0 - 128, 0, (bf16*)sB[0], 1536, tid);
  stage8k(X, ldx, row0, 64, (bf16*)sA[1], 0, tid);
  stage8k(X, ldx, row0, 64, (bf16*)sA[1], 512, tid);
  stage8k(Gt, ldw, fcol0, 64, (bf16*)sB[1], 0, tid);
  stage8k(Gt, ldw, fcol0, 64, (bf16*)sB[1], 512, tid);
  stage8k(Ut, ldw, fcol0 - 128, 64, (bf16*)sB[1], 1024, tid);
  stage8k(Ut, ldw, fcol0 - 128, 64, (bf16*)sB[1], 1536, tid);
  asm volatile("s_waitcnt vmcnt(6)" ::: "memory");
  __builtin_amdgcn_s_barrier();

  bf16x8 a[4][2], b[4][2];

  for (int t = 0; t < NK; ++t) {
    bf16* aCur = (bf16*)sA[t & 1];
    bf16* bCur = (bf16*)sB[t & 1];
    bf16* aNxt = (bf16*)sA[(t + 1) & 1];
    const long k1 = (long)((t + 1) % NK) * 64;  // wrap: tail stages land harmlessly
    const long k2 = (long)((t + 2) % NK) * 64;

    // ---- phase 1: read A-mh0 (8) + B-gate (4); stage (t+1)A1; MFMA Q(mh0, gate)
#pragma unroll
    for (int m = 0; m < 4; ++m)
#pragma unroll
      for (int kk = 0; kk < 2; ++kk)
        a[m][kk] = ldsfrag(aCur, m * 32 + wm * 16 + fr, kk, fg);
#pragma unroll
    for (int n = 0; n < 2; ++n)
#pragma unroll
      for (int kk = 0; kk < 2; ++kk)
        b[n][kk] = ldsfrag(bCur, n * 64 + wn * 16 + fr, kk, fg);
    stage8k(X, ldx, row0, k1, aNxt, 1024, tid);
    stage8k(X, ldx, row0, k1, aNxt, 1536, tid);
    PHASE_MFMA_BEGIN();
#pragma unroll
    for (int m = 0; m < 4; ++m)
#pragma unroll
      for (int n = 0; n < 2; ++n)
#pragma unroll
        for (int kk = 0; kk < 2; ++kk)
          acc[m][n] = MFMA(a[m][kk], b[n][kk], acc[m][n]);
    PHASE_MFMA_END();

    // ---- phase 2: read B-up (4); stage (t+2)A0; MFMA Q(mh0, up)
#pragma unroll
    for (int n = 2; n < 4; ++n)
#pragma unroll
      for (int kk = 0; kk < 2; ++kk)
        b[n][kk] = ldsfrag(bCur, n * 64 + wn * 16 + fr, kk, fg);
    stage8k(X, ldx, row0, k2, aCur, 0, tid);
    stage8k(X, ldx, row0, k2, aCur, 512, tid);
    PHASE_MFMA_BEGIN();
#pragma unroll
    for (int m = 0; m < 4; ++m)
#pragma unroll
      for (int n = 2; n < 4; ++n)
#pragma unroll
        for (int kk = 0; kk < 2; ++kk)
          acc[m][n] = MFMA(a[m][kk], b[n][kk], acc[m][n]);
    PHASE_MFMA_END();

    // ---- phase 3: read A-mh1 (8); stage (t+2)B-gate; MFMA Q(mh1, up)
#pragma unroll
    for (int m = 0; m < 4; ++m)
#pragma unroll
      for (int kk = 0; kk < 2; ++kk)
        a[m][kk] = ldsfrag(aCur, 128 + m * 32 + wm * 16 + fr, kk, fg);
    stage8k(Gt, ldw, fcol0, k2, bCur, 0, tid);
    stage8k(Gt, ldw, fcol0, k2, bCur, 512, tid);
    PHASE_MFMA_BEGIN();
#pragma unroll
    for (int m = 0; m < 4; ++m)
#pragma unroll
      for (int n = 2; n < 4; ++n)
#pragma unroll
        for (int kk = 0; kk < 2; ++kk)
          acc[4 + m][n] = MFMA(a[m][kk], b[n][kk], acc[4 + m][n]);
    PHASE_MFMA_END();

    // ---- phase 4: stage (t+2)B-up; vmcnt(6); MFMA Q(mh1, gate)
    stage8k(Ut, ldw, fcol0 - 128, k2, bCur, 1024, tid);
    stage8k(Ut, ldw, fcol0 - 128, k2, bCur, 1536, tid);
    asm volatile("s_waitcnt vmcnt(6)" ::: "memory");
    PHASE_MFMA_BEGIN();
#pragma unroll
    for (int m = 0; m < 4; ++m)
#pragma unroll
      for (int n = 0; n < 2; ++n)
#pragma unroll
        for (int kk = 0; kk < 2; ++kk)
          acc[4 + m][n] = MFMA(a[m][kk], b[n][kk], acc[4 + m][n]);
    PHASE_MFMA_END();
  }

  // epilogue: H = bf16(silu(gate) * up) — register-only pairing
#pragma unroll
  for (int m = 0; m < 8; ++m) {
    const long rbase = row0 + m * 32 + wm * 16 + fg * 4;
#pragma unroll
    for (int n = 0; n < 2; ++n) {
      const long c = fcol0 + n * 64 + wn * 16 + fr;
#pragma unroll
      for (int i = 0; i < 4; ++i) {
        float gv = acc[m][n][i];
        float uv = acc[m][n + 2][i];
        float hv = (gv / (1.0f + __expf(-gv))) * uv;
        H[(rbase + i) * ldh + c] = __float2bfloat16(hv);
      }
    }
  }
}

// ---------------------------------------------------------------- GEMM2: out = routing*(H @ Wd)  (8-phase, m201 geometry)
// A:[T][ldh], Bt:[DM][lddt]. Tile 256x256, per-wave 128x64, acc[8][4].
// XCD-partitioned: xcd owns 2 col-blocks (512 cols); bm co-temporal.
__global__ __launch_bounds__(512, 2) void gemm_down_kernel(
    const bf16* __restrict__ A, const bf16* __restrict__ Bt,
    const float* __restrict__ routing, float* __restrict__ out,
    long ldh, long lddt) {
  __shared__ __align__(16) bf16 sA[2][256 * 64];   // 64 KiB
  __shared__ __align__(16) bf16 sB[2][256 * 64];   // 64 KiB

  const int tid = threadIdx.x;
  const int lane = tid & 63, wid = tid >> 6;
  const int wm = wid >> 2, wn = wid & 3;
  const int fr = lane & 15, fg = lane >> 4;

  const int id = blockIdx.x;
  const int xcd = id & 7, j = id >> 3;
  const int bm = j >> 1, bnl = j & 1;
  const long row0 = (long)bm * 256;
  const long col0 = (long)(xcd * 2 + bnl) * 256;
  const int NK = DFF / 64;  // 224

  f32x4 acc[8][4];
  const f32x4 z = {0.f, 0.f, 0.f, 0.f};
#pragma unroll
  for (int m = 0; m < 8; ++m)
#pragma unroll
    for (int n = 0; n < 4; ++n) acc[m][n] = z;

  // prologue: K0 full (A0,A1,B0,B1), K1 partial (A0,B0,B1)
  stage8k(A, ldh, row0, 0, (bf16*)sA[0], 0, tid);
  stage8k(A, ldh, row0, 0, (bf16*)sA[0], 512, tid);
  stage8k(A, ldh, row0, 0, (bf16*)sA[0], 1024, tid);
  stage8k(A, ldh, row0, 0, (bf16*)sA[0], 1536, tid);
  stage8k(Bt, lddt, col0, 0, (bf16*)sB[0], 0, tid);
  stage8k(Bt, lddt, col0, 0, (bf16*)sB[0], 512, tid);
  stage8k(Bt, lddt, col0, 0, (bf16*)sB[0], 1024, tid);
  stage8k(Bt, lddt, col0, 0, (bf16*)sB[0], 1536, tid);
  stage8k(A, ldh, row0, 64, (bf16*)sA[1], 0, tid);
  stage8k(A, ldh, row0, 64, (bf16*)sA[1], 512, tid);
  stage8k(Bt, lddt, col0, 64, (bf16*)sB[1], 0, tid);
  stage8k(Bt, lddt, col0, 64, (bf16*)sB[1], 512, tid);
  stage8k(Bt, lddt, col0, 64, (bf16*)sB[1], 1024, tid);
  stage8k(Bt, lddt, col0, 64, (bf16*)sB[1], 1536, tid);
  asm volatile("s_waitcnt vmcnt(6)" ::: "memory");
  __builtin_amdgcn_s_barrier();

  bf16x8 a[4][2], b[4][2];

  for (int t = 0; t < NK; ++t) {
    bf16* aCur = (bf16*)sA[t & 1];
    bf16* bCur = (bf16*)sB[t & 1];
    bf16* aNxt = (bf16*)sA[(t + 1) & 1];
    const long k1 = (long)((t + 1) % NK) * 64;
    const long k2 = (long)((t + 2) % NK) * 64;

    // ---- phase 1: read A-mh0 (8) + B-nh0 (4); stage (t+1)A1; MFMA Q(mh0,nh0)
#pragma unroll
    for (int m = 0; m < 4; ++m)
#pragma unroll
      for (int kk = 0; kk < 2; ++kk)
        a[m][kk] = ldsfrag(aCur, m * 32 + wm * 16 + fr, kk, fg);
#pragma unroll
    for (int n = 0; n < 2; ++n)
#pragma unroll
      for (int kk = 0; kk < 2; ++kk)
        b[n][kk] = ldsfrag(bCur, n * 64 + wn * 16 + fr, kk, fg);
    stage8k(A, ldh, row0, k1, aNxt, 1024, tid);
    stage8k(A, ldh, row0, k1, aNxt, 1536, tid);
    PHASE_MFMA_BEGIN();
#pragma unroll
    for (int m = 0; m < 4; ++m)
#pragma unroll
      for (int n = 0; n < 2; ++n)
#pragma unroll
        for (int kk = 0; kk < 2; ++kk)
          acc[m][n] = MFMA(a[m][kk], b[n][kk], acc[m][n]);
    PHASE_MFMA_END();

    // ---- phase 2: read B-nh1 (4); stage (t+2)A0; MFMA Q(mh0,nh1)
#pragma unroll
    for (int n = 2; n < 4; ++n)
#pragma unroll
      for (int kk = 0; kk < 2; ++kk)
        b[n][kk] = ldsfrag(bCur, n * 64 + wn * 16 + fr, kk, fg);
    stage8k(A, ldh, row0, k2, aCur, 0, tid);
    stage8k(A, ldh, row0, k2, aCur, 512, tid);
    PHASE_MFMA_BEGIN();
#pragma unroll
    for (int m = 0; m < 4; ++m)
#pragma unroll
      for (int n = 2; n < 4; ++n)
#pragma unroll
        for (int kk = 0; kk < 2; ++kk)
          acc[m][n] = MFMA(a[m][kk], b[n][kk], acc[m][n]);
    PHASE_MFMA_END();

    // ---- phase 3: read A-mh1 (8); stage (t+2)B0; MFMA Q(mh1,nh1)
#pragma unroll
    for (int m = 0; m < 4; ++m)
#pragma unroll
      for (int kk = 0; kk < 2; ++kk)
        a[m][kk] = ldsfrag(aCur, 128 + m * 32 + wm * 16 + fr, kk, fg);
    stage8k(Bt, lddt, col0, k2, bCur, 0, tid);
    stage8k(Bt, lddt, col0, k2, bCur, 512, tid);
    PHASE_MFMA_BEGIN();
#pragma unroll
    for (int m = 0; m < 4; ++m)
#pragma unroll
      for (int n = 2; n < 4; ++n)
#pragma unroll
        for (int kk = 0; kk < 2; ++kk)
          acc[4 + m][n] = MFMA(a[m][kk], b[n][kk], acc[4 + m][n]);
    PHASE_MFMA_END();

    // ---- phase 4: stage (t+2)B1; vmcnt(6); MFMA Q(mh1,nh0)
    stage8k(Bt, lddt, col0, k2, bCur, 1024, tid);
    stage8k(Bt, lddt, col0, k2, bCur, 1536, tid);
    asm volatile("s_waitcnt vmcnt(6)" ::: "memory");
    PHASE_MFMA_BEGIN();
#pragma unroll
    for (int m = 0; m < 4; ++m)
#pragma unroll
      for (int n = 0; n < 2; ++n)
#pragma unroll
        for (int kk = 0; kk < 2; ++kk)
          acc[4 + m][n] = MFMA(a[m][kk], b[n][kk], acc[4 + m][n]);
    PHASE_MFMA_END();
  }

  // epilogue: out = routing[r] * acc  (d_out is unpadded [T][DM])
#pragma unroll
  for (int m = 0; m < 8; ++m) {
    const long r0w = row0 + m * 32 + wm * 16 + fg * 4;
#pragma unroll
    for (int i = 0; i < 4; ++i) {
      const long r = r0w + i;
      const float rv = routing[r];
#pragma unroll
      for (int n = 0; n < 4; ++n)
        out[r * DM + (col0 + n * 64 + wn * 16 + fr)] = rv * acc[m][n][i];
    }
  }
}

// ---------------------------------------------------------------- launch
extern "C" void kernel_launch(void* const* d_in, const int* in_sizes, int n_in,
                              void* d_out, int out_size, void* d_ws, size_t ws_size,
                              hipStream_t stream) {
  const float* X  = (const float*)d_in[0];
  const float* rw = (const float*)d_in[1];
  const float* Wg = (const float*)d_in[2];
  const float* Wu = (const float*)d_in[3];
  const float* Wd = (const float*)d_in[4];
  float* out = (float*)d_out;

  // Padded leading dims (break power-of-2 row strides: 4160*2=65*128B,
  // 14400*2=225*128B). Fall back to unpadded if workspace is tight.
  long XL = DM + 64, WL = DM + 64, DL = DFF + 64, HL = DFF + 64;
  {
    size_t need = 2ull * ((size_t)T_DIM * XL + 2ull * (size_t)DFF * WL +
                          (size_t)DM * DL + (size_t)T_DIM * HL);
    if (ws_size < need) { XL = DM; WL = DM; DL = DFF; HL = DFF; }
  }

  char* ws = (char*)d_ws;
  size_t off = 0;
  bf16* Xb = (bf16*)(ws + off); off += (size_t)T_DIM * XL * 2;
  bf16* GT = (bf16*)(ws + off); off += (size_t)DFF * WL * 2;
  bf16* UT = (bf16*)(ws + off); off += (size_t)DFF * WL * 2;
  bf16* DT = (bf16*)(ws + off); off += (size_t)DM * DL * 2;
  bf16* Hb = (bf16*)(ws + off); off += (size_t)T_DIM * HL * 2;

  cast_pad_kernel<<<2048, 256, 0, stream>>>(X, Xb, XL, T_DIM * DM / 8);
  dim3 tpb(32, 8);
  transpose_cast_kernel<<<dim3(DFF / 32, DM / 32), tpb, 0, stream>>>(Wg, GT, DM, DFF, WL);
  transpose_cast_kernel<<<dim3(DFF / 32, DM / 32), tpb, 0, stream>>>(Wu, UT, DM, DFF, WL);
  transpose_cast_kernel<<<dim3(DM / 32, DFF / 32), tpb, 0, stream>>>(Wd, DT, DFF, DM, DL);

  gemm_gateup_kernel<<<(T_DIM / 256) * (DFF / 128), 512, 0, stream>>>(
      Xb, GT, UT, Hb, XL, WL, HL);
  gemm_down_kernel<<<(T_DIM / 256) * (DM / 256), 512, 0, stream>>>(
      Hb, DT, rw, out, HL, DL);
}